// Round 4
// baseline (453.569 us; speedup 1.0000x reference)
//
// SelfAttentionWide (B=4, T=1024, E=512, H=8 wide heads) — MI355X gfx950
// Round 7: Round-6 z-fused gemm256 with the LDS bug fixed: the final manual
// half-slab double-added the B-region offset (16384 + brd, but brd already
// contains +16384) -> OOB LDS read -> garbage last K-slice of V. Now uses the
// same slab_+ard/slab_+brd addressing as HALF_ITER.
// Scores/softmax/PV/unify unchanged. fp32 in/out, bf16 MFMA core.
#include <hip/hip_runtime.h>
#include <stdint.h>

typedef unsigned short u16;
typedef unsigned int u32;
typedef __bf16 bf16_t;
typedef __attribute__((ext_vector_type(8))) bf16_t bf16x8;
typedef __attribute__((ext_vector_type(4))) float floatx4;

__device__ __forceinline__ u16 f2b(float f) {
  u32 u = __float_as_uint(f);
  return (u16)((u + 0x7fffu + ((u >> 16) & 1u)) >> 16);
}

// async 16B/lane global->LDS; LDS dest is wave-uniform base + lane*16
__device__ __forceinline__ void gload_lds16(const u16* g, u16* l) {
  __builtin_amdgcn_global_load_lds(
      (const __attribute__((address_space(1))) u32*)g,
      (__attribute__((address_space(3))) u32*)l, 16, 0, 0);
}

// fused fp32 -> bf16: blockIdx.y selects tensor (all 2M elements)
__global__ __launch_bounds__(256) void cvt_kernel(
    const float* __restrict__ s0, const float* __restrict__ s1,
    const float* __restrict__ s2, const float* __restrict__ s3,
    const float* __restrict__ s4, u16* __restrict__ dbase) {
  const int which = blockIdx.y;
  const float* s = which == 0 ? s0 : which == 1 ? s1 : which == 2 ? s2
                 : which == 3 ? s3 : s4;
  u16* d = dbase + (long)which * 2097152;
  const int i = blockIdx.x * 256 + threadIdx.x;
  const float4 v = ((const float4*)s)[i];
  ushort4 o;
  o.x = f2b(v.x); o.y = f2b(v.y); o.z = f2b(v.z); o.w = f2b(v.w);
  ((ushort4*)d)[i] = o;
}

// out[4096 x 512] fp32 <- broadcast bias rows (pre-pass for split-K atomic unify)
__global__ __launch_bounds__(256) void init_out_kernel(float* __restrict__ out,
                                                       const float* __restrict__ bias) {
  const int i = blockIdx.x * 256 + threadIdx.x;  // 524288 float4s
  const int c4 = i & 127;
  ((float4*)out)[i] = ((const float4*)bias)[c4];
}

enum { A_PLAIN = 0, A_HEADBLK = 1 };   // HEADBLK: A is O in (b,h,t,e), logical (r=(b,t), k=(h,e))
enum { B_PLAIN = 0, B_TRANS = 1 };     // TRANS: B global is (k,n) row-major (V), stage transposed
enum { C_BF16_PLAIN = 0, C_BF16_BHTE = 1, C_F32_PLAIN = 2, C_F32_ATOMIC = 3 };

// ============================================================================
// z-fused 256x256 pipelined GEMM: for z in {q,k,v}: C_z = A @ B_z^T (bf16->bf16
// BHTE). 512 thr = 8 waves (2M x 4N); per-wave 128x64 out = acc[8][4] frags.
// Pipeline unit = 32-col HALF-SLAB (A 256x32 + B 256x32, 4 gload calls).
// GLOBAL slab index h = z*16 + kk, h in [0,48); slot(h) = slot(h mod 4) since
// 16 % 4 == 0 => 4 LDS slots (2buf x 2ks) rotate seamlessly ACROSS z.
// Stage slab h+3 while computing h => ~4-phase window; vmcnt steady 8,
// tail (z=2 only) 8,4,0. In-loop epilogue stores are NEWER than prefetched
// loads => vmcnt(8) still guarantees slab h+1 landed (oldest-first).
// LDS swizzle (T2, 64B rows): slot s at row r holds col-group s ^ ((r>>1)&3);
// staging pre-swizzles per-lane GLOBAL col (LDS dest linear, G21). Conflict-
// free verified round 2 (SQ_LDS_BANK_CONFLICT = 0).
// XCD swizzle: XCD x owns tiles m in [4(x>>1),+4), n in [8(x&1),+8):
// A 1MB + B 2MB = 3MB < 4MiB L2/XCD; A stays L2-hot across all z.
// ============================================================================
#define MFMA16(MB)                                                                                 \
  do {                                                                                             \
    acc[(MB) + 0][0] = __builtin_amdgcn_mfma_f32_16x16x32_bf16(A0, B0, acc[(MB) + 0][0], 0, 0, 0); \
    acc[(MB) + 0][1] = __builtin_amdgcn_mfma_f32_16x16x32_bf16(A0, B1, acc[(MB) + 0][1], 0, 0, 0); \
    acc[(MB) + 0][2] = __builtin_amdgcn_mfma_f32_16x16x32_bf16(A0, B2, acc[(MB) + 0][2], 0, 0, 0); \
    acc[(MB) + 0][3] = __builtin_amdgcn_mfma_f32_16x16x32_bf16(A0, B3, acc[(MB) + 0][3], 0, 0, 0); \
    acc[(MB) + 1][0] = __builtin_amdgcn_mfma_f32_16x16x32_bf16(A1, B0, acc[(MB) + 1][0], 0, 0, 0); \
    acc[(MB) + 1][1] = __builtin_amdgcn_mfma_f32_16x16x32_bf16(A1, B1, acc[(MB) + 1][1], 0, 0, 0); \
    acc[(MB) + 1][2] = __builtin_amdgcn_mfma_f32_16x16x32_bf16(A1, B2, acc[(MB) + 1][2], 0, 0, 0); \
    acc[(MB) + 1][3] = __builtin_amdgcn_mfma_f32_16x16x32_bf16(A1, B3, acc[(MB) + 1][3], 0, 0, 0); \
    acc[(MB) + 2][0] = __builtin_amdgcn_mfma_f32_16x16x32_bf16(A2, B0, acc[(MB) + 2][0], 0, 0, 0); \
    acc[(MB) + 2][1] = __builtin_amdgcn_mfma_f32_16x16x32_bf16(A2, B1, acc[(MB) + 2][1], 0, 0, 0); \
    acc[(MB) + 2][2] = __builtin_amdgcn_mfma_f32_16x16x32_bf16(A2, B2, acc[(MB) + 2][2], 0, 0, 0); \
    acc[(MB) + 2][3] = __builtin_amdgcn_mfma_f32_16x16x32_bf16(A2, B3, acc[(MB) + 2][3], 0, 0, 0); \
    acc[(MB) + 3][0] = __builtin_amdgcn_mfma_f32_16x16x32_bf16(A3, B0, acc[(MB) + 3][0], 0, 0, 0); \
    acc[(MB) + 3][1] = __builtin_amdgcn_mfma_f32_16x16x32_bf16(A3, B1, acc[(MB) + 3][1], 0, 0, 0); \
    acc[(MB) + 3][2] = __builtin_amdgcn_mfma_f32_16x16x32_bf16(A3, B2, acc[(MB) + 3][2], 0, 0, 0); \
    acc[(MB) + 3][3] = __builtin_amdgcn_mfma_f32_16x16x32_bf16(A3, B3, acc[(MB) + 3][3], 0, 0, 0); \
  } while (0)

// stage one 128-row x 32-col call (c=0/1) of GLOBAL slab hn into its LDS slot
#define STG_A(hn, c)                                                             \
  {                                                                              \
    const int kn_ = (hn) & 15;                                                   \
    gload_lds16(ag + (long)((c) << 7) * lda + (kn_ << 5),                        \
                &lds[(((kn_ >> 1) & 1) << 15) + ((kn_ & 1) << 13) + ((c) << 12) + ls]); \
  }
#define STG_B(hn, c)                                                             \
  {                                                                              \
    const int kn_ = (hn) & 15, zn_ = (hn) >> 4;                                  \
    gload_lds16(bg + (long)zn_ * b_zstride + (long)((c) << 7) * ldb + (kn_ << 5),\
                &lds[(((kn_ >> 1) & 1) << 15) + 16384 + ((kn_ & 1) << 13) + ((c) << 12) + ls]); \
  }

#define PHASE_SYNC_PRE()                                \
  __builtin_amdgcn_s_barrier();                         \
  asm volatile("s_waitcnt lgkmcnt(0)" ::: "memory");    \
  __builtin_amdgcn_sched_barrier(0);                    \
  __builtin_amdgcn_s_setprio(1)

#define PHASE_SYNC_POST()                               \
  __builtin_amdgcn_s_setprio(0);                        \
  __builtin_amdgcn_s_barrier();                         \
  __builtin_amdgcn_sched_barrier(0)

// one half-slab (read slot from kk, stage global slab hn if DO_STAGE):
#define HALF_ITER(kk, hn, DO_STAGE, VM)                               \
  {                                                                   \
    const int slab_ = ((((kk) >> 1) & 1) << 15) + (((kk) & 1) << 13); \
    const u16* la_ = &lds[slab_ + ard];                               \
    const u16* lb_ = &lds[slab_ + brd];                               \
    A0 = *(const bf16x8*)(la_ + 0 * 512);                             \
    A1 = *(const bf16x8*)(la_ + 1 * 512);                             \
    A2 = *(const bf16x8*)(la_ + 2 * 512);                             \
    A3 = *(const bf16x8*)(la_ + 3 * 512);                             \
    B0 = *(const bf16x8*)(lb_ + 0 * 512);                             \
    B1 = *(const bf16x8*)(lb_ + 1 * 512);                             \
    B2 = *(const bf16x8*)(lb_ + 2 * 512);                             \
    B3 = *(const bf16x8*)(lb_ + 3 * 512);                             \
    if (DO_STAGE) { STG_A((hn), 0); STG_A((hn), 1); }                 \
    PHASE_SYNC_PRE();                                                 \
    MFMA16(0);                                                        \
    PHASE_SYNC_POST();                                                \
    A0 = *(const bf16x8*)(la_ + 4 * 512);                             \
    A1 = *(const bf16x8*)(la_ + 5 * 512);                             \
    A2 = *(const bf16x8*)(la_ + 6 * 512);                             \
    A3 = *(const bf16x8*)(la_ + 7 * 512);                             \
    if (DO_STAGE) { STG_B((hn), 0); STG_B((hn), 1); }                 \
    PHASE_SYNC_PRE();                                                 \
    MFMA16(4);                                                        \
    __builtin_amdgcn_s_setprio(0);                                    \
    asm volatile("s_waitcnt vmcnt(" #VM ")" ::: "memory");            \
    __builtin_amdgcn_s_barrier();                                     \
    __builtin_amdgcn_sched_barrier(0);                                \
  }

__global__ __launch_bounds__(512, 2) void gemm256_kernel(
    const u16* __restrict__ A, int lda,
    const u16* __restrict__ B, int ldb, long b_zstride,
    u16* __restrict__ C, long c_zstride) {
  __shared__ u16 lds[65536];  // 128 KB

  const int tid = threadIdx.x;
  const int wid = tid >> 6, lane = tid & 63;
  const int lrow = lane & 15, quad = lane >> 4;
  const int wm = wid >> 2, wn = wid & 3;

  // L2-capacity XCD swizzle: XCD x owns 4m x 8n tiles (3MB working set < 4MiB)
  const int o = blockIdx.x;
  const int xcd = o & 7, j = o >> 3;
  const int m0 = (((xcd >> 1) << 2) | (j >> 3)) << 8;
  const int n0 = (((xcd & 1) << 3) | (j & 7)) << 8;

  // staging: lane -> (row16 = lane>>2, slot = lane&3); LDS dest linear, global
  // source col-group inverse-swizzled: slot ^ ((row16>>1)&3)  [G21 / m173]
  const int scol = (((lane & 3) ^ ((lane >> 3) & 3)) << 3);
  const u16* ag = A + (long)(m0 + (wid << 4) + (lane >> 2)) * lda + scol;
  const u16* bg = B + (long)(n0 + (wid << 4) + (lane >> 2)) * ldb + scol;
  const int ls = wid << 9;  // elems: wave chunk within a 4096-elem (128-row) call

  // fragment read bases ([256][32] row-major per half-slab), slot swizzled
  const int qsw = ((quad ^ ((lrow >> 1) & 3)) << 3);
  const int ard = (((wm << 7) + lrow) << 5) + qsw;
  const int brd = 16384 + (((wn << 6) + lrow) << 5) + qsw;

  floatx4 acc[8][4];
#pragma unroll
  for (int i = 0; i < 8; ++i)
#pragma unroll
    for (int jj = 0; jj < 4; ++jj) acc[i][jj] = (floatx4)0.0f;

  // ---- prologue: stage global slabs 0,1,2 (12 calls), wait slab 0 (oldest 4)
  STG_A(0, 0); STG_A(0, 1); STG_B(0, 0); STG_B(0, 1);
  STG_A(1, 0); STG_A(1, 1); STG_B(1, 0); STG_B(1, 1);
  STG_A(2, 0); STG_A(2, 1); STG_B(2, 0); STG_B(2, 1);
  asm volatile("s_waitcnt vmcnt(8)" ::: "memory");
  __builtin_amdgcn_s_barrier();
  __builtin_amdgcn_sched_barrier(0);

  bf16x8 A0, A1, A2, A3, B0, B1, B2, B3;

  for (int z = 0; z < 3; ++z) {
    const int hb = z << 4;
    if (z < 2) {
      for (int kk = 0; kk < 16; ++kk) HALF_ITER(kk, hb + kk + 3, true, 8);
    } else {
      for (int kk = 0; kk < 13; ++kk) HALF_ITER(kk, hb + kk + 3, true, 8);
      HALF_ITER(13, 0, false, 4);
      HALF_ITER(14, 0, false, 0);
      {  // last half-slab (kk=15): slot = buf1(32768) + ks1(8192); brd already
         // includes the +16384 B-region offset (round-6 bug: it was added twice)
        const int slab_ = 32768 + 8192;
        const u16* la_ = &lds[slab_ + ard];
        const u16* lb_ = &lds[slab_ + brd];
        A0 = *(const bf16x8*)(la_ + 0 * 512);
        A1 = *(const bf16x8*)(la_ + 1 * 512);
        A2 = *(const bf16x8*)(la_ + 2 * 512);
        A3 = *(const bf16x8*)(la_ + 3 * 512);
        B0 = *(const bf16x8*)(lb_ + 0 * 512);
        B1 = *(const bf16x8*)(lb_ + 1 * 512);
        B2 = *(const bf16x8*)(lb_ + 2 * 512);
        B3 = *(const bf16x8*)(lb_ + 3 * 512);
        PHASE_SYNC_PRE();
        MFMA16(0);
        PHASE_SYNC_POST();
        A0 = *(const bf16x8*)(la_ + 4 * 512);
        A1 = *(const bf16x8*)(la_ + 5 * 512);
        A2 = *(const bf16x8*)(la_ + 6 * 512);
        A3 = *(const bf16x8*)(la_ + 7 * 512);
        PHASE_SYNC_PRE();
        MFMA16(4);
        __builtin_amdgcn_s_setprio(0);
      }
    }

    // ---- per-z epilogue: BHTE scatter, D row = quad*4+r, col = lrow (m89);
    // stores are newer than prefetched loads => later vmcnt(8) stays safe.
#pragma unroll
    for (int mi = 0; mi < 8; ++mi) {
#pragma unroll
      for (int ni = 0; ni < 4; ++ni) {
        const int cg = n0 + (wn << 6) + (ni << 4) + lrow;
        const long cbase = (long)z * c_zstride + (long)(cg >> 9) * 524288 + (cg & 511);
#pragma unroll
        for (int r = 0; r < 4; ++r) {
          const int rg = m0 + (wm << 7) + (mi << 4) + (quad << 2) + r;
          C[cbase + (long)(rg >> 10) * 4194304 + (long)(rg & 1023) * 512] = f2b(acc[mi][ni][r]);
        }
        acc[mi][ni] = (floatx4)0.0f;  // re-zero for next z
      }
    }
  }
}

// C[M x N] = A[M x K] @ B[N x K]^T  (bf16 in, fp32 acc), tile 128x128x32,
// 256 thr = 4 waves (2x2), wave = 4x4 of 16x16x32 MFMA.
// SPLITK: blockIdx.z selects a K-chunk of size K (param = chunk), epilogue atomics.
template <int AMODE, int BMODE, int CMODE, bool CAUSAL_SKIP, bool PV_KLIM, bool HAS_BIAS,
          bool SPLITK>
__global__ __launch_bounds__(256, 2) void gemm_kernel(
    const u16* __restrict__ A, int lda, long a_zstride,
    const u16* __restrict__ B, int ldb, long b_zstride,
    void* __restrict__ C, int ldc, long c_zstride,
    const float* __restrict__ bias, int K, float scale) {
  const int bn = blockIdx.x, bm = blockIdx.y, bz = blockIdx.z;
  if (CAUSAL_SKIP && bn > bm) return;

  int kTiles = K >> 5;
  if (PV_KLIM) kTiles = (bm + 1) * 4;  // rows q in [bm*128,+128) only need k < (bm+1)*128
  const int kbase = SPLITK ? bz * K : 0;

  const u16* Ab = A + (SPLITK ? 0 : (long)bz * a_zstride);
  const u16* Bb = B + (SPLITK ? 0 : (long)bz * b_zstride);

  constexpr int BSTR = (BMODE == B_TRANS) ? 40 : 32;  // pad to 40 (80B, 16B-mult) vs conflicts
  __shared__ u16 sA[128 * 32];
  __shared__ u16 sB[128 * BSTR];

  const int tid = threadIdx.x;
  const int wid = tid >> 6;
  const int lane = tid & 63;
  const int lrow = lane & 15;
  const int quad = lane >> 4;
  const int wm = wid >> 1, wn = wid & 1;
  const int m0 = bm * 128, n0 = bn * 128;

  const int sgr = lane >> 2;        // staging row within 16-row chunk
  const int sgc = (lane & 3) << 3;  // staging col (8 bf16 = 16B)

  floatx4 acc[4][4];
#pragma unroll
  for (int i = 0; i < 4; ++i)
#pragma unroll
    for (int j = 0; j < 4; ++j) acc[i][j] = (floatx4)0.0f;

  for (int kt = 0; kt < kTiles; ++kt) {
    const int k0 = kbase + (kt << 5);
    // ---- stage A tile (async, 16B/lane): wave wid covers rows [wid*32, wid*32+32)
#pragma unroll
    for (int j = 0; j < 2; ++j) {
      const int r = wid * 32 + j * 16 + sgr;
      const u16* g;
      if constexpr (AMODE == A_PLAIN) {
        g = Ab + (long)(m0 + r) * lda + (k0 + sgc);
      } else {
        const int rg = m0 + r, kg = k0 + sgc;
        g = Ab + (long)((rg >> 10) * 8 + (kg >> 9)) * 524288 +
            (long)(rg & 1023) * 512 + (kg & 511);
      }
      gload_lds16(g, &sA[(wid * 32 + j * 16) * 32]);
    }
    // ---- stage B tile
    if constexpr (BMODE == B_PLAIN) {
#pragma unroll
      for (int j = 0; j < 2; ++j) {
        const int r = wid * 32 + j * 16 + sgr;
        const u16* g = Bb + (long)(n0 + r) * ldb + (k0 + sgc);
        gload_lds16(g, &sB[(wid * 32 + j * 16) * 32]);
      }
    } else {
      // transpose-stage V chunk: global (k0+tr, n0+te..te+15) -> sB[n][k]
      const int tr = tid & 31, te = (tid >> 5) << 4;
      const u16* g = Bb + (long)(k0 + tr) * ldb + (n0 + te);
      union { uint4 v[2]; u16 s[16]; } tmp;
      tmp.v[0] = *(const uint4*)g;
      tmp.v[1] = *(const uint4*)(g + 8);
#pragma unroll
      for (int i = 0; i < 16; ++i) sB[(te + i) * BSTR + tr] = tmp.s[i];
    }
    __syncthreads();

    bf16x8 af[4], bfr[4];
#pragma unroll
    for (int i = 0; i < 4; ++i)
      af[i] = *(const bf16x8*)&sA[(wm * 64 + i * 16 + lrow) * 32 + (quad << 3)];
#pragma unroll
    for (int i = 0; i < 4; ++i)
      bfr[i] = *(const bf16x8*)&sB[(wn * 64 + i * 16 + lrow) * BSTR + (quad << 3)];
#pragma unroll
    for (int mi = 0; mi < 4; ++mi)
#pragma unroll
      for (int ni = 0; ni < 4; ++ni)
        acc[mi][ni] = __builtin_amdgcn_mfma_f32_16x16x32_bf16(af[mi], bfr[ni], acc[mi][ni], 0, 0, 0);
    __syncthreads();
  }

  // ---- epilogue: D[row=(quad*4+r)][col=lrow] per 16x16 tile (m89-verified layout)
#pragma unroll
  for (int mi = 0; mi < 4; ++mi) {
#pragma unroll
    for (int ni = 0; ni < 4; ++ni) {
      const int cg = n0 + wn * 64 + ni * 16 + lrow;
      float bv = 0.0f;
      if constexpr (HAS_BIAS) bv = bias[cg];
#pragma unroll
      for (int r = 0; r < 4; ++r) {
        const int rg = m0 + wm * 64 + mi * 16 + quad * 4 + r;
        const float val = acc[mi][ni][r] * scale + bv;
        if constexpr (CMODE == C_F32_PLAIN) {
          ((float*)C)[(long)bz * c_zstride + (long)rg * ldc + cg] = val;
        } else if constexpr (CMODE == C_F32_ATOMIC) {
          atomicAdd(&((float*)C)[(long)rg * ldc + cg], val);
        } else if constexpr (CMODE == C_BF16_PLAIN) {
          ((u16*)C)[(long)bz * c_zstride + (long)rg * ldc + cg] = f2b(val);
        } else {  // C_BF16_BHTE: (r=(b,t), c=(h,e)) -> (b,h,t,e), + z offset
          const long idx = (long)bz * c_zstride +
                           (long)((rg >> 10) * 8 + (cg >> 9)) * 524288 +
                           (long)(rg & 1023) * 512 + (cg & 511);
          ((u16*)C)[idx] = f2b(val);
        }
      }
    }
  }
}

// causal row softmax over S fp32 row q (cols 0..q), write P bf16 in place (lda=2048),
// zero-fill P cols q+1 .. round_up_128(q+1) so the PV GEMM can read full k-tiles.
__global__ __launch_bounds__(256) void softmax_kernel(float* __restrict__ S) {
  const int q = blockIdx.x;
  const long zoff = (long)blockIdx.y * 1048576;
  const float* Srow = S + zoff + (long)q * 1024;
  u16* Prow = (u16*)(S + zoff) + (long)q * 2048;
  const int tid = threadIdx.x;
  const int ncol = q + 1;

  float v[4];
  float m = -3.4e38f;
#pragma unroll
  for (int i = 0; i < 4; ++i) {
    const int c = tid + (i << 8);
    v[i] = (c < ncol) ? Srow[c] : -3.4e38f;
    m = fmaxf(m, v[i]);
  }
#pragma unroll
  for (int off = 32; off > 0; off >>= 1) m = fmaxf(m, __shfl_xor(m, off));
  __shared__ float red[8];
  const int w = tid >> 6;
  if ((tid & 63) == 0) red[w] = m;
  __syncthreads();
  m = fmaxf(fmaxf(red[0], red[1]), fmaxf(red[2], red[3]));

  float s = 0.0f, e[4];
#pragma unroll
  for (int i = 0; i < 4; ++i) {
    const int c = tid + (i << 8);
    e[i] = (c < ncol) ? __expf(v[i] - m) : 0.0f;
    s += e[i];
  }
#pragma unroll
  for (int off = 32; off > 0; off >>= 1) s += __shfl_xor(s, off);
  if ((tid & 63) == 0) red[4 + w] = s;
  __syncthreads();
  s = red[4] + red[5] + red[6] + red[7];
  const float inv = 1.0f / s;
  const int nzend = ((q >> 7) + 1) << 7;
#pragma unroll
  for (int i = 0; i < 4; ++i) {
    const int c = tid + (i << 8);
    if (c < ncol) Prow[c] = f2b(e[i] * inv);
    else if (c < nzend) Prow[c] = 0;
  }
}

extern "C" void kernel_launch(void* const* d_in, const int* in_sizes, int n_in,
                              void* d_out, int out_size, void* d_ws, size_t ws_size,
                              hipStream_t stream) {
  const float* x   = (const float*)d_in[0];
  const float* w_k = (const float*)d_in[1];
  const float* w_q = (const float*)d_in[2];
  const float* w_v = (const float*)d_in[3];
  const float* w_u = (const float*)d_in[4];
  const float* b_u = (const float*)d_in[5];
  float* out = (float*)d_out;
  char* ws = (char*)d_ws;

  const long MB = 1048576;
  // ws layout (bytes): xb 0, wqb 4, wkb 8, wvb 12, wub 16 (bf16, contiguous q/k/v for z-fused
  // QKV gemm); Q 20..52, K 52..84, V 84..116, O 116..148, S fp32 @148
  u16* xb  = (u16*)(ws);
  u16* wqb = (u16*)(ws + 4 * MB);
  u16* wub = (u16*)(ws + 16 * MB);
  u16* Q   = (u16*)(ws + 20 * MB);
  u16* Kb  = (u16*)(ws + 52 * MB);
  u16* V   = (u16*)(ws + 84 * MB);
  u16* O   = (u16*)(ws + 116 * MB);
  float* S = (float*)(ws + 148 * MB);

  // attention group size (bh per pass), by available scratch for S (G*4MB at +148MB)
  int G;
  if (ws_size >= (size_t)(282 * MB)) G = 32;      // full
  else if (ws_size >= (size_t)(180 * MB)) G = 8;  // per-batch
  else G = 1;                                     // per-(b,h)

  const dim3 blk(256);
  const float s2 = 0.044194173824159216f;  // 512^{-1/2} == (e^{-1/4})^2 folded into scores

  // fused fp32 -> bf16 conversions: dest order matches ws layout (x,q,k,v,u)
  cvt_kernel<<<dim3(2048, 5), blk, 0, stream>>>(x, w_q, w_k, w_v, w_u, xb);

  // fused QKV projections (z-fused in-kernel): grid 256 blocks of 512 thr,
  // 128KB LDS, 1 block/CU, single 48-half-slab pipeline
  gemm256_kernel<<<dim3(256), dim3(512), 0, stream>>>(
      xb, 512, wqb, 512, 2097152, Q, 16777216);

  for (int g = 0; g < 32 / G; ++g) {
    const long off = (long)g * G * 524288;
    // scores: S = s2 * Q_bh @ K_bh^T, lower-triangular blocks only
    gemm_kernel<A_PLAIN, B_PLAIN, C_F32_PLAIN, true, false, false, false>
        <<<dim3(8, 8, G), blk, 0, stream>>>(Q + off, 512, 524288, Kb + off, 512, 524288,
                                            S, 1024, 1048576, nullptr, 512, s2);
    softmax_kernel<<<dim3(1024, G), blk, 0, stream>>>(S);
    // O_bh = P @ V_bh  (P bf16 in-place over S, lda=2048; V transpose-staged)
    gemm_kernel<A_PLAIN, B_TRANS, C_BF16_PLAIN, false, true, false, false>
        <<<dim3(4, 8, G), blk, 0, stream>>>((const u16*)S, 2048, 2097152, V + off, 512, 524288,
                                            O + off, 512, 524288, nullptr, 1024, 1.0f);
  }

  // unify: out(fp32) = O2d @ w_u^T + b_u, split-K x4 (K-chunk 1024) for occupancy:
  // grid 4x32x4 = 512 blocks (was 128 @ 5.4% occupancy). Bias via init, partials via atomicAdd.
  init_out_kernel<<<2048, blk, 0, stream>>>(out, b_u);
  gemm_kernel<A_HEADBLK, B_PLAIN, C_F32_ATOMIC, false, false, false, true>
      <<<dim3(4, 32, 4), blk, 0, stream>>>(O, 0, 0, wub, 4096, 0, out, 512, 0,
                                           nullptr, 1024, 1.0f);
}

// Round 5
// 303.816 us; speedup vs baseline: 1.4929x; 1.4929x over previous
//
// SelfAttentionWide (B=4, T=1024, E=512, H=8 wide heads) — MI355X gfx950
// Round 8: FLASH-FUSED attention middle. One 256-block kernel (1/CU) replaces
// scores+softmax+PV and the 4-pass G-loop: per block = (bh, q-tile pair
// (qt,15-qt) of 64 rows -> uniform 9 k-tiles). S-phase streams Q/K e-slabs
// (3-slot LDS rotation, counted vmcnt(3)); online softmax in registers
// (shfl k-reduce + 2 small LDS reduces); P->LDS swizzled; PV streams V^T
// e-chunks (2-slot, reads-retired-before-stage order). V^T built by a small
// LDS-tiled transpose kernel. Eliminates S (fp32 75+67MB) and P (34+34MB)
// traffic + ~10 dispatches. QKV gemm256 / cvt / init / unify unchanged.
#include <hip/hip_runtime.h>
#include <stdint.h>

typedef unsigned short u16;
typedef unsigned int u32;
typedef __bf16 bf16_t;
typedef __attribute__((ext_vector_type(8))) bf16_t bf16x8;
typedef __attribute__((ext_vector_type(4))) float floatx4;

__device__ __forceinline__ u16 f2b(float f) {
  u32 u = __float_as_uint(f);
  return (u16)((u + 0x7fffu + ((u >> 16) & 1u)) >> 16);
}

// async 16B/lane global->LDS; LDS dest is wave-uniform base + lane*16
__device__ __forceinline__ void gload_lds16(const u16* g, u16* l) {
  __builtin_amdgcn_global_load_lds(
      (const __attribute__((address_space(1))) u32*)g,
      (__attribute__((address_space(3))) u32*)l, 16, 0, 0);
}

// fused fp32 -> bf16: blockIdx.y selects tensor (all 2M elements)
__global__ __launch_bounds__(256) void cvt_kernel(
    const float* __restrict__ s0, const float* __restrict__ s1,
    const float* __restrict__ s2, const float* __restrict__ s3,
    const float* __restrict__ s4, u16* __restrict__ dbase) {
  const int which = blockIdx.y;
  const float* s = which == 0 ? s0 : which == 1 ? s1 : which == 2 ? s2
                 : which == 3 ? s3 : s4;
  u16* d = dbase + (long)which * 2097152;
  const int i = blockIdx.x * 256 + threadIdx.x;
  const float4 v = ((const float4*)s)[i];
  ushort4 o;
  o.x = f2b(v.x); o.y = f2b(v.y); o.z = f2b(v.z); o.w = f2b(v.w);
  ((ushort4*)d)[i] = o;
}

// out[4096 x 512] fp32 <- broadcast bias rows (pre-pass for split-K atomic unify)
__global__ __launch_bounds__(256) void init_out_kernel(float* __restrict__ out,
                                                       const float* __restrict__ bias) {
  const int i = blockIdx.x * 256 + threadIdx.x;  // 524288 float4s
  const int c4 = i & 127;
  ((float4*)out)[i] = ((const float4*)bias)[c4];
}

enum { A_PLAIN = 0, A_HEADBLK = 1 };
enum { B_PLAIN = 0, B_TRANS = 1 };
enum { C_BF16_PLAIN = 0, C_BF16_BHTE = 1, C_F32_PLAIN = 2, C_F32_ATOMIC = 3 };

// ============================================================================
// z-fused 256x256 pipelined QKV GEMM (round-7, verified).
// ============================================================================
#define MFMA16(MB)                                                                                 \
  do {                                                                                             \
    acc[(MB) + 0][0] = __builtin_amdgcn_mfma_f32_16x16x32_bf16(A0, B0, acc[(MB) + 0][0], 0, 0, 0); \
    acc[(MB) + 0][1] = __builtin_amdgcn_mfma_f32_16x16x32_bf16(A0, B1, acc[(MB) + 0][1], 0, 0, 0); \
    acc[(MB) + 0][2] = __builtin_amdgcn_mfma_f32_16x16x32_bf16(A0, B2, acc[(MB) + 0][2], 0, 0, 0); \
    acc[(MB) + 0][3] = __builtin_amdgcn_mfma_f32_16x16x32_bf16(A0, B3, acc[(MB) + 0][3], 0, 0, 0); \
    acc[(MB) + 1][0] = __builtin_amdgcn_mfma_f32_16x16x32_bf16(A1, B0, acc[(MB) + 1][0], 0, 0, 0); \
    acc[(MB) + 1][1] = __builtin_amdgcn_mfma_f32_16x16x32_bf16(A1, B1, acc[(MB) + 1][1], 0, 0, 0); \
    acc[(MB) + 1][2] = __builtin_amdgcn_mfma_f32_16x16x32_bf16(A1, B2, acc[(MB) + 1][2], 0, 0, 0); \
    acc[(MB) + 1][3] = __builtin_amdgcn_mfma_f32_16x16x32_bf16(A1, B3, acc[(MB) + 1][3], 0, 0, 0); \
    acc[(MB) + 2][0] = __builtin_amdgcn_mfma_f32_16x16x32_bf16(A2, B0, acc[(MB) + 2][0], 0, 0, 0); \
    acc[(MB) + 2][1] = __builtin_amdgcn_mfma_f32_16x16x32_bf16(A2, B1, acc[(MB) + 2][1], 0, 0, 0); \
    acc[(MB) + 2][2] = __builtin_amdgcn_mfma_f32_16x16x32_bf16(A2, B2, acc[(MB) + 2][2], 0, 0, 0); \
    acc[(MB) + 2][3] = __builtin_amdgcn_mfma_f32_16x16x32_bf16(A2, B3, acc[(MB) + 2][3], 0, 0, 0); \
    acc[(MB) + 3][0] = __builtin_amdgcn_mfma_f32_16x16x32_bf16(A3, B0, acc[(MB) + 3][0], 0, 0, 0); \
    acc[(MB) + 3][1] = __builtin_amdgcn_mfma_f32_16x16x32_bf16(A3, B1, acc[(MB) + 3][1], 0, 0, 0); \
    acc[(MB) + 3][2] = __builtin_amdgcn_mfma_f32_16x16x32_bf16(A3, B2, acc[(MB) + 3][2], 0, 0, 0); \
    acc[(MB) + 3][3] = __builtin_amdgcn_mfma_f32_16x16x32_bf16(A3, B3, acc[(MB) + 3][3], 0, 0, 0); \
  } while (0)

#define STG_A(hn, c)                                                             \
  {                                                                              \
    const int kn_ = (hn) & 15;                                                   \
    gload_lds16(ag + (long)((c) << 7) * lda + (kn_ << 5),                        \
                &lds[(((kn_ >> 1) & 1) << 15) + ((kn_ & 1) << 13) + ((c) << 12) + ls]); \
  }
#define STG_B(hn, c)                                                             \
  {                                                                              \
    const int kn_ = (hn) & 15, zn_ = (hn) >> 4;                                  \
    gload_lds16(bg + (long)zn_ * b_zstride + (long)((c) << 7) * ldb + (kn_ << 5),\
                &lds[(((kn_ >> 1) & 1) << 15) + 16384 + ((kn_ & 1) << 13) + ((c) << 12) + ls]); \
  }

#define PHASE_SYNC_PRE()                                \
  __builtin_amdgcn_s_barrier();                         \
  asm volatile("s_waitcnt lgkmcnt(0)" ::: "memory");    \
  __builtin_amdgcn_sched_barrier(0);                    \
  __builtin_amdgcn_s_setprio(1)

#define PHASE_SYNC_POST()                               \
  __builtin_amdgcn_s_setprio(0);                        \
  __builtin_amdgcn_s_barrier();                         \
  __builtin_amdgcn_sched_barrier(0)

#define HALF_ITER(kk, hn, DO_STAGE, VM)                               \
  {                                                                   \
    const int slab_ = ((((kk) >> 1) & 1) << 15) + (((kk) & 1) << 13); \
    const u16* la_ = &lds[slab_ + ard];                               \
    const u16* lb_ = &lds[slab_ + brd];                               \
    A0 = *(const bf16x8*)(la_ + 0 * 512);                             \
    A1 = *(const bf16x8*)(la_ + 1 * 512);                             \
    A2 = *(const bf16x8*)(la_ + 2 * 512);                             \
    A3 = *(const bf16x8*)(la_ + 3 * 512);                             \
    B0 = *(const bf16x8*)(lb_ + 0 * 512);                             \
    B1 = *(const bf16x8*)(lb_ + 1 * 512);                             \
    B2 = *(const bf16x8*)(lb_ + 2 * 512);                             \
    B3 = *(const bf16x8*)(lb_ + 3 * 512);                             \
    if (DO_STAGE) { STG_A((hn), 0); STG_A((hn), 1); }                 \
    PHASE_SYNC_PRE();                                                 \
    MFMA16(0);                                                        \
    PHASE_SYNC_POST();                                                \
    A0 = *(const bf16x8*)(la_ + 4 * 512);                             \
    A1 = *(const bf16x8*)(la_ + 5 * 512);                             \
    A2 = *(const bf16x8*)(la_ + 6 * 512);                             \
    A3 = *(const bf16x8*)(la_ + 7 * 512);                             \
    if (DO_STAGE) { STG_B((hn), 0); STG_B((hn), 1); }                 \
    PHASE_SYNC_PRE();                                                 \
    MFMA16(4);                                                        \
    __builtin_amdgcn_s_setprio(0);                                    \
    asm volatile("s_waitcnt vmcnt(" #VM ")" ::: "memory");            \
    __builtin_amdgcn_s_barrier();                                     \
    __builtin_amdgcn_sched_barrier(0);                                \
  }

__global__ __launch_bounds__(512, 2) void gemm256_kernel(
    const u16* __restrict__ A, int lda,
    const u16* __restrict__ B, int ldb, long b_zstride,
    u16* __restrict__ C, long c_zstride) {
  __shared__ u16 lds[65536];  // 128 KB

  const int tid = threadIdx.x;
  const int wid = tid >> 6, lane = tid & 63;
  const int lrow = lane & 15, quad = lane >> 4;
  const int wm = wid >> 2, wn = wid & 3;

  const int o = blockIdx.x;
  const int xcd = o & 7, j = o >> 3;
  const int m0 = (((xcd >> 1) << 2) | (j >> 3)) << 8;
  const int n0 = (((xcd & 1) << 3) | (j & 7)) << 8;

  const int scol = (((lane & 3) ^ ((lane >> 3) & 3)) << 3);
  const u16* ag = A + (long)(m0 + (wid << 4) + (lane >> 2)) * lda + scol;
  const u16* bg = B + (long)(n0 + (wid << 4) + (lane >> 2)) * ldb + scol;
  const int ls = wid << 9;

  const int qsw = ((quad ^ ((lrow >> 1) & 3)) << 3);
  const int ard = (((wm << 7) + lrow) << 5) + qsw;
  const int brd = 16384 + (((wn << 6) + lrow) << 5) + qsw;

  floatx4 acc[8][4];
#pragma unroll
  for (int i = 0; i < 8; ++i)
#pragma unroll
    for (int jj = 0; jj < 4; ++jj) acc[i][jj] = (floatx4)0.0f;

  STG_A(0, 0); STG_A(0, 1); STG_B(0, 0); STG_B(0, 1);
  STG_A(1, 0); STG_A(1, 1); STG_B(1, 0); STG_B(1, 1);
  STG_A(2, 0); STG_A(2, 1); STG_B(2, 0); STG_B(2, 1);
  asm volatile("s_waitcnt vmcnt(8)" ::: "memory");
  __builtin_amdgcn_s_barrier();
  __builtin_amdgcn_sched_barrier(0);

  bf16x8 A0, A1, A2, A3, B0, B1, B2, B3;

  for (int z = 0; z < 3; ++z) {
    const int hb = z << 4;
    if (z < 2) {
      for (int kk = 0; kk < 16; ++kk) HALF_ITER(kk, hb + kk + 3, true, 8);
    } else {
      for (int kk = 0; kk < 13; ++kk) HALF_ITER(kk, hb + kk + 3, true, 8);
      HALF_ITER(13, 0, false, 4);
      HALF_ITER(14, 0, false, 0);
      {  // last half-slab (kk=15): slot = buf1(32768) + ks1(8192)
        const int slab_ = 32768 + 8192;
        const u16* la_ = &lds[slab_ + ard];
        const u16* lb_ = &lds[slab_ + brd];
        A0 = *(const bf16x8*)(la_ + 0 * 512);
        A1 = *(const bf16x8*)(la_ + 1 * 512);
        A2 = *(const bf16x8*)(la_ + 2 * 512);
        A3 = *(const bf16x8*)(la_ + 3 * 512);
        B0 = *(const bf16x8*)(lb_ + 0 * 512);
        B1 = *(const bf16x8*)(lb_ + 1 * 512);
        B2 = *(const bf16x8*)(lb_ + 2 * 512);
        B3 = *(const bf16x8*)(lb_ + 3 * 512);
        PHASE_SYNC_PRE();
        MFMA16(0);
        PHASE_SYNC_POST();
        A0 = *(const bf16x8*)(la_ + 4 * 512);
        A1 = *(const bf16x8*)(la_ + 5 * 512);
        A2 = *(const bf16x8*)(la_ + 6 * 512);
        A3 = *(const bf16x8*)(la_ + 7 * 512);
        PHASE_SYNC_PRE();
        MFMA16(4);
        __builtin_amdgcn_s_setprio(0);
      }
    }

#pragma unroll
    for (int mi = 0; mi < 8; ++mi) {
#pragma unroll
      for (int ni = 0; ni < 4; ++ni) {
        const int cg = n0 + (wn << 6) + (ni << 4) + lrow;
        const long cbase = (long)z * c_zstride + (long)(cg >> 9) * 524288 + (cg & 511);
#pragma unroll
        for (int r = 0; r < 4; ++r) {
          const int rg = m0 + (wm << 7) + (mi << 4) + (quad << 2) + r;
          C[cbase + (long)(rg >> 10) * 4194304 + (long)(rg & 1023) * 512] = f2b(acc[mi][ni][r]);
        }
        acc[mi][ni] = (floatx4)0.0f;
      }
    }
  }
}

// ============================================================================
// V transpose: V (bh,t,e) -> VT (bh,e,t). 64x64 tiles via XOR-swizzled LDS.
// ============================================================================
__global__ __launch_bounds__(256) void vt_kernel(const u16* __restrict__ V,
                                                 u16* __restrict__ VT) {
  __shared__ u16 tl[4096];  // [64][64], groups-of-8 XOR-swizzled by row&7
  const long base = (long)blockIdx.z * 524288;
  const int t0 = blockIdx.x << 6, e0 = blockIdx.y << 6;
  const int tid = threadIdx.x;
  const int r = tid >> 3, g = tid & 7;
#pragma unroll
  for (int h = 0; h < 2; ++h) {
    const int row = r + (h << 5);
    const uint4 v = *(const uint4*)&V[base + (long)(t0 + row) * 512 + e0 + (g << 3)];
    *(uint4*)&tl[(row << 6) + ((g ^ (row & 7)) << 3)] = v;
  }
  __syncthreads();
#pragma unroll
  for (int h = 0; h < 2; ++h) {
    const int el = r + (h << 5);
    union { u16 us[8]; uint4 v; } o;
#pragma unroll
    for (int j = 0; j < 8; ++j) {
      const int trow = (g << 3) + j;
      o.us[j] = tl[(trow << 6) + ((((el >> 3) ^ (trow & 7)) << 3) + (el & 7))];
    }
    *(uint4*)&VT[base + (long)(e0 + el) * 1024 + t0 + (g << 3)] = o.v;
  }
}

// ============================================================================
// Flash attention, wide heads (D=512). Block = (bh, q-tile pair (qt,15-qt)),
// q-tile 64 rows, k-tiles of 128 -> uniform 9 k-tiles/block. 8 waves (2m x 4n).
// LDS 152KB: Sstg 3x12288 (Q[2][64][32]+K[2][128][32] per slab) | P [4][64][32]
// | V 2x[4][128][32]. All [*][32] rows use the verified T2 swizzle pair
// (scol pre-swizzled global source, qsw on reads). red buffers overlay Sstg.
// ============================================================================
#define FS_STG(es)                                                          \
  {                                                                         \
    const int sl_ = (es) % 3;                                               \
    gload_lds16(qgq + (es) * 64, &lds[sl_ * 12288 + ls]);                   \
    gload_lds16(kgj + (es) * 64, &lds[sl_ * 12288 + 4096 + ls]);            \
    gload_lds16(kgj + (es) * 64 + 32, &lds[sl_ * 12288 + 8192 + ls]);       \
  }
#define FV_STG(c)                                                           \
  {                                                                         \
    const int vb_ = 45056 + ((c) & 1) * 16384;                              \
    const u16* vgc_ = vgj + (c) * 131072;                                   \
    gload_lds16(vgc_, &lds[vb_ + ls]);                                      \
    gload_lds16(vgc_ + 32, &lds[vb_ + 4096 + ls]);                          \
    gload_lds16(vgc_ + 64, &lds[vb_ + 8192 + ls]);                          \
    gload_lds16(vgc_ + 96, &lds[vb_ + 12288 + ls]);                         \
  }

__global__ __launch_bounds__(512, 2) void flash_kernel(
    const u16* __restrict__ Qg, const u16* __restrict__ Kg,
    const u16* __restrict__ VTg, u16* __restrict__ Og) {
  __shared__ u16 lds[77824];  // 152 KB

  const int tid = threadIdx.x;
  const int wid = tid >> 6, lane = tid & 63;
  const int lrow = lane & 15, quad = lane >> 4;
  const int wm = wid >> 2, wn = wid & 3;

  const int blk = blockIdx.x;
  const int bh = ((blk & 7) << 2) | ((blk >> 3) & 3);  // 4 bh per XCD
  const int pr = blk >> 5;                              // q-tile pair id

  const long base = (long)bh * 524288;
  const u16* Qb = Qg + base;
  const u16* Kb = Kg + base;
  const u16* Vb = VTg + base;
  u16* Ob = Og + base;

  const int scol = (((lane & 3) ^ ((lane >> 3) & 3)) << 3);
  const int ls = wid << 9;
  const int qsw = ((quad ^ ((lrow >> 1) & 3)) << 3);

  // staging bases (G21: pre-swizzled global col, linear LDS dest)
  const u16* qg0 = Qb + (long)(((wid & 3) << 4) + (lane >> 2)) * 512 + ((wid >> 2) << 5) + scol;
  const u16* kg0 = Kb + (long)((wid << 4) + (lane >> 2)) * 512 + scol;
  const u16* vg0 = Vb + (long)((wid << 4) + (lane >> 2)) * 1024 + scol;

  const int a_rd = ((wm << 5) + lrow) * 32 + qsw;          // Q slab local
  const int b_rd = ((wn << 5) + lrow) * 32 + qsw;          // K/V slab local
  const int p_rd = 36864 + ((wm << 5) + lrow) * 32 + qsw;  // P region
  float* red_max = (float*)lds;          // [64][4] overlay on Sstg slot0
  float* red_sum = ((float*)lds) + 256;  // [64][4]
  const float s2 = 0.044194173824159216f;

  for (int ht = 0; ht < 2; ++ht) {
    const int qt = ht ? (15 - pr) : pr;
    const int q0 = qt << 6;
    const int nk = (qt >> 1) + 1;
    const u16* qgq = qg0 + (long)q0 * 512;

    floatx4 oa[2][4][2];
#pragma unroll
    for (int a = 0; a < 2; ++a)
#pragma unroll
      for (int b = 0; b < 4; ++b)
#pragma unroll
        for (int c = 0; c < 2; ++c) oa[a][b][c] = (floatx4)0.0f;
    float m_st[2][4], l_st[2][4];
#pragma unroll
    for (int a = 0; a < 2; ++a)
#pragma unroll
      for (int r = 0; r < 4; ++r) { m_st[a][r] = -3.0e38f; l_st[a][r] = 0.0f; }

    for (int j = 0; j < nk; ++j) {
      const int k0 = j << 7;
      const bool maskt = (j == nk - 1);
      const u16* kgj = kg0 + (long)k0 * 512;
      const u16* vgj = vg0 + k0;

      floatx4 sacc[2][2];
      sacc[0][0] = sacc[0][1] = sacc[1][0] = sacc[1][1] = (floatx4)0.0f;

      // ---- S-phase: S(64x128) = Q @ K^T over e=512, 8 e-slabs, 3-slot rot.
      FS_STG(0); FS_STG(1);
      asm volatile("s_waitcnt vmcnt(3)" ::: "memory");
      __builtin_amdgcn_s_barrier();
      __builtin_amdgcn_sched_barrier(0);
#pragma unroll
      for (int es = 0; es < 8; ++es) {
        const int sb = (es % 3) * 12288;
        bf16x8 qa[2][2], kb[2][2];
#pragma unroll
        for (int ks = 0; ks < 2; ++ks) {
#pragma unroll
          for (int mi = 0; mi < 2; ++mi)
            qa[ks][mi] = *(const bf16x8*)&lds[sb + ks * 2048 + a_rd + mi * 512];
#pragma unroll
          for (int ni = 0; ni < 2; ++ni)
            kb[ks][ni] = *(const bf16x8*)&lds[sb + 4096 + ks * 4096 + b_rd + ni * 512];
        }
        if (es < 6) FS_STG(es + 2);
        __builtin_amdgcn_s_barrier();
        asm volatile("s_waitcnt lgkmcnt(0)" ::: "memory");
        __builtin_amdgcn_sched_barrier(0);
        __builtin_amdgcn_s_setprio(1);
#pragma unroll
        for (int ks = 0; ks < 2; ++ks)
#pragma unroll
          for (int mi = 0; mi < 2; ++mi)
#pragma unroll
            for (int ni = 0; ni < 2; ++ni)
              sacc[mi][ni] = __builtin_amdgcn_mfma_f32_16x16x32_bf16(
                  qa[ks][mi], kb[ks][ni], sacc[mi][ni], 0, 0, 0);
        __builtin_amdgcn_s_setprio(0);
        if (es < 6) { asm volatile("s_waitcnt vmcnt(3)" ::: "memory"); }
        else if (es == 6) { asm volatile("s_waitcnt vmcnt(0)" ::: "memory"); }
        __builtin_amdgcn_s_barrier();
        __builtin_amdgcn_sched_barrier(0);
      }

      // V prefetch (chunks 0,1 fly during softmax; V region untouched below)
      FV_STG(0); FV_STG(1);

      // ---- online softmax (S layout: row=32wm+16mi+quad*4+r, col=32wn+16ni+lrow)
      float sv[2][2][4];
#pragma unroll
      for (int mi = 0; mi < 2; ++mi)
#pragma unroll
        for (int ni = 0; ni < 2; ++ni)
#pragma unroll
          for (int r = 0; r < 4; ++r) {
            float s = sacc[mi][ni][r] * s2;
            if (maskt) {
              const int kc = k0 + (wn << 5) + (ni << 4) + lrow;
              const int qr = q0 + (wm << 5) + (mi << 4) + (quad << 2) + r;
              if (kc > qr) s = -3.0e38f;
            }
            sv[mi][ni][r] = s;
          }
      float rm[2][4];
#pragma unroll
      for (int mi = 0; mi < 2; ++mi)
#pragma unroll
        for (int r = 0; r < 4; ++r) {
          float v = fmaxf(sv[mi][0][r], sv[mi][1][r]);
          v = fmaxf(v, __shfl_xor(v, 1));
          v = fmaxf(v, __shfl_xor(v, 2));
          v = fmaxf(v, __shfl_xor(v, 4));
          v = fmaxf(v, __shfl_xor(v, 8));
          rm[mi][r] = v;
        }
      if (lrow == 0) {
#pragma unroll
        for (int mi = 0; mi < 2; ++mi)
#pragma unroll
          for (int r = 0; r < 4; ++r)
            red_max[(((wm << 5) + (mi << 4) + (quad << 2) + r) << 2) + wn] = rm[mi][r];
      }
      asm volatile("s_waitcnt lgkmcnt(0)" ::: "memory");
      __builtin_amdgcn_s_barrier();
      float mnew[2][4], resc[2][4];
#pragma unroll
      for (int mi = 0; mi < 2; ++mi)
#pragma unroll
        for (int r = 0; r < 4; ++r) {
          const float4 v4 =
              *(const float4*)&red_max[(((wm << 5) + (mi << 4) + (quad << 2) + r) << 2)];
          const float tm = fmaxf(fmaxf(v4.x, v4.y), fmaxf(v4.z, v4.w));
          const float mn = fmaxf(m_st[mi][r], tm);
          mnew[mi][r] = mn;
          resc[mi][r] = __expf(m_st[mi][r] - mn);
          m_st[mi][r] = mn;
        }
      float ps[2][4];
#pragma unroll
      for (int mi = 0; mi < 2; ++mi)
#pragma unroll
        for (int r = 0; r < 4; ++r) {
          const float p0 = __expf(sv[mi][0][r] - mnew[mi][r]);
          const float p1 = __expf(sv[mi][1][r] - mnew[mi][r]);
          sv[mi][0][r] = p0;
          sv[mi][1][r] = p1;
          float v = p0 + p1;
          v += __shfl_xor(v, 1);
          v += __shfl_xor(v, 2);
          v += __shfl_xor(v, 4);
          v += __shfl_xor(v, 8);
          ps[mi][r] = v;
        }
      if (lrow == 0) {
#pragma unroll
        for (int mi = 0; mi < 2; ++mi)
#pragma unroll
          for (int r = 0; r < 4; ++r)
            red_sum[(((wm << 5) + (mi << 4) + (quad << 2) + r) << 2) + wn] = ps[mi][r];
      }
      // O rescale hides under the sum-reduce
#pragma unroll
      for (int mi = 0; mi < 2; ++mi)
#pragma unroll
        for (int c = 0; c < 4; ++c)
#pragma unroll
          for (int n2 = 0; n2 < 2; ++n2)
#pragma unroll
            for (int r = 0; r < 4; ++r) oa[mi][c][n2][r] *= resc[mi][r];
      asm volatile("s_waitcnt lgkmcnt(0)" ::: "memory");
      __builtin_amdgcn_s_barrier();
#pragma unroll
      for (int mi = 0; mi < 2; ++mi)
#pragma unroll
        for (int r = 0; r < 4; ++r) {
          const float4 v4 =
              *(const float4*)&red_sum[(((wm << 5) + (mi << 4) + (quad << 2) + r) << 2)];
          l_st[mi][r] = l_st[mi][r] * resc[mi][r] + (v4.x + v4.y + v4.z + v4.w);
        }
      // P -> LDS [4ks][64][32] bf16 (ks = wn), swizzled to match pa reads
#pragma unroll
      for (int mi = 0; mi < 2; ++mi)
#pragma unroll
        for (int ni = 0; ni < 2; ++ni)
#pragma unroll
          for (int r = 0; r < 4; ++r) {
            const int qrow = (wm << 5) + (mi << 4) + (quad << 2) + r;
            const int c32 = (ni << 4) + lrow;
            const int slot = (c32 >> 3) ^ ((qrow >> 1) & 3);
            lds[36864 + (wn << 11) + qrow * 32 + (slot << 3) + (c32 & 7)] =
                f2b(sv[mi][ni][r]);
          }
      asm volatile("s_waitcnt lgkmcnt(0)" ::: "memory");
      asm volatile("s_waitcnt vmcnt(4)" ::: "memory");  // V chunk0 landed
      __builtin_amdgcn_s_barrier();
      __builtin_amdgcn_sched_barrier(0);

      // ---- PV: O(64x512) += P(64x128) @ VT-chunks, 2-slot stream
      bf16x8 pa[2][4];
#pragma unroll
      for (int mi = 0; mi < 2; ++mi)
#pragma unroll
        for (int ks = 0; ks < 4; ++ks)
          pa[mi][ks] = *(const bf16x8*)&lds[p_rd + mi * 512 + ks * 2048];
#pragma unroll
      for (int c = 0; c < 4; ++c) {
        const int vb0 = 45056 + (c & 1) * 16384;
        bf16x8 vb[2][4];
#pragma unroll
        for (int n2 = 0; n2 < 2; ++n2)
#pragma unroll
          for (int ks = 0; ks < 4; ++ks)
            vb[n2][ks] = *(const bf16x8*)&lds[vb0 + ks * 4096 + b_rd + n2 * 512];
        // reads must retire in ALL waves before overwriting slot c&1 (dist-2)
        asm volatile("s_waitcnt lgkmcnt(0)" ::: "memory");
        __builtin_amdgcn_sched_barrier(0);
        __builtin_amdgcn_s_barrier();
        if (c < 2) FV_STG(c + 2);
        __builtin_amdgcn_s_setprio(1);
#pragma unroll
        for (int ks = 0; ks < 4; ++ks)
#pragma unroll
          for (int mi = 0; mi < 2; ++mi)
#pragma unroll
            for (int n2 = 0; n2 < 2; ++n2)
              oa[mi][c][n2] = __builtin_amdgcn_mfma_f32_16x16x32_bf16(
                  pa[mi][ks], vb[n2][ks], oa[mi][c][n2], 0, 0, 0);
        __builtin_amdgcn_s_setprio(0);
        if (c < 2) { asm volatile("s_waitcnt vmcnt(4)" ::: "memory"); }
        else if (c == 2) { asm volatile("s_waitcnt vmcnt(0)" ::: "memory"); }
        __builtin_amdgcn_s_barrier();
        __builtin_amdgcn_sched_barrier(0);
      }
    }  // k-tiles

    // ---- finalize: O /= l, store bf16 to (bh,t,e)
    float inv[2][4];
#pragma unroll
    for (int mi = 0; mi < 2; ++mi)
#pragma unroll
      for (int r = 0; r < 4; ++r) inv[mi][r] = 1.0f / l_st[mi][r];
#pragma unroll
    for (int mi = 0; mi < 2; ++mi)
#pragma unroll
      for (int c = 0; c < 4; ++c)
#pragma unroll
        for (int n2 = 0; n2 < 2; ++n2)
#pragma unroll
          for (int r = 0; r < 4; ++r) {
            const int trow = q0 + (wm << 5) + (mi << 4) + (quad << 2) + r;
            const int e = (c << 7) + (wn << 5) + (n2 << 4) + lrow;
            Ob[(long)trow * 512 + e] = f2b(oa[mi][c][n2][r] * inv[mi][r]);
          }
  }  // q-tile pair
}

// ============================================================================
// 128x128 GEMM (kept for the unify projection only).
// ============================================================================
template <int AMODE, int BMODE, int CMODE, bool CAUSAL_SKIP, bool PV_KLIM, bool HAS_BIAS,
          bool SPLITK>
__global__ __launch_bounds__(256, 2) void gemm_kernel(
    const u16* __restrict__ A, int lda, long a_zstride,
    const u16* __restrict__ B, int ldb, long b_zstride,
    void* __restrict__ C, int ldc, long c_zstride,
    const float* __restrict__ bias, int K, float scale) {
  const int bn = blockIdx.x, bm = blockIdx.y, bz = blockIdx.z;
  if (CAUSAL_SKIP && bn > bm) return;

  int kTiles = K >> 5;
  if (PV_KLIM) kTiles = (bm + 1) * 4;
  const int kbase = SPLITK ? bz * K : 0;

  const u16* Ab = A + (SPLITK ? 0 : (long)bz * a_zstride);
  const u16* Bb = B + (SPLITK ? 0 : (long)bz * b_zstride);

  constexpr int BSTR = (BMODE == B_TRANS) ? 40 : 32;
  __shared__ u16 sA[128 * 32];
  __shared__ u16 sB[128 * BSTR];

  const int tid = threadIdx.x;
  const int wid = tid >> 6;
  const int lane = tid & 63;
  const int lrow = lane & 15;
  const int quad = lane >> 4;
  const int wm = wid >> 1, wn = wid & 1;
  const int m0 = bm * 128, n0 = bn * 128;

  const int sgr = lane >> 2;
  const int sgc = (lane & 3) << 3;

  floatx4 acc[4][4];
#pragma unroll
  for (int i = 0; i < 4; ++i)
#pragma unroll
    for (int j = 0; j < 4; ++j) acc[i][j] = (floatx4)0.0f;

  for (int kt = 0; kt < kTiles; ++kt) {
    const int k0 = kbase + (kt << 5);
#pragma unroll
    for (int j = 0; j < 2; ++j) {
      const int r = wid * 32 + j * 16 + sgr;
      const u16* g;
      if constexpr (AMODE == A_PLAIN) {
        g = Ab + (long)(m0 + r) * lda + (k0 + sgc);
      } else {
        const int rg = m0 + r, kg = k0 + sgc;
        g = Ab + (long)((rg >> 10) * 8 + (kg >> 9)) * 524288 +
            (long)(rg & 1023) * 512 + (kg & 511);
      }
      gload_lds16(g, &sA[(wid * 32 + j * 16) * 32]);
    }
    if constexpr (BMODE == B_PLAIN) {
#pragma unroll
      for (int j = 0; j < 2; ++j) {
        const int r = wid * 32 + j * 16 + sgr;
        const u16* g = Bb + (long)(n0 + r) * ldb + (k0 + sgc);
        gload_lds16(g, &sB[(wid * 32 + j * 16) * 32]);
      }
    } else {
      const int tr = tid & 31, te = (tid >> 5) << 4;
      const u16* g = Bb + (long)(k0 + tr) * ldb + (n0 + te);
      union { uint4 v[2]; u16 s[16]; } tmp;
      tmp.v[0] = *(const uint4*)g;
      tmp.v[1] = *(const uint4*)(g + 8);
#pragma unroll
      for (int i = 0; i < 16; ++i) sB[(te + i) * BSTR + tr] = tmp.s[i];
    }
    __syncthreads();

    bf16x8 af[4], bfr[4];
#pragma unroll
    for (int i = 0; i < 4; ++i)
      af[i] = *(const bf16x8*)&sA[(wm * 64 + i * 16 + lrow) * 32 + (quad << 3)];
#pragma unroll
    for (int i = 0; i < 4; ++i)
      bfr[i] = *(const bf16x8*)&sB[(wn * 64 + i * 16 + lrow) * BSTR + (quad << 3)];
#pragma unroll
    for (int mi = 0; mi < 4; ++mi)
#pragma unroll
      for (int ni = 0; ni < 4; ++ni)
        acc[mi][ni] = __builtin_amdgcn_mfma_f32_16x16x32_bf16(af[mi], bfr[ni], acc[mi][ni], 0, 0, 0);
    __syncthreads();
  }

#pragma unroll
  for (int mi = 0; mi < 4; ++mi) {
#pragma unroll
    for (int ni = 0; ni < 4; ++ni) {
      const int cg = n0 + wn * 64 + ni * 16 + lrow;
      float bv = 0.0f;
      if constexpr (HAS_BIAS) bv = bias[cg];
#pragma unroll
      for (int r = 0; r < 4; ++r) {
        const int rg = m0 + wm * 64 + mi * 16 + quad * 4 + r;
        const float val = acc[mi][ni][r] * scale + bv;
        if constexpr (CMODE == C_F32_PLAIN) {
          ((float*)C)[(long)bz * c_zstride + (long)rg * ldc + cg] = val;
        } else if constexpr (CMODE == C_F32_ATOMIC) {
          atomicAdd(&((float*)C)[(long)rg * ldc + cg], val);
        } else if constexpr (CMODE == C_BF16_PLAIN) {
          ((u16*)C)[(long)bz * c_zstride + (long)rg * ldc + cg] = f2b(val);
        } else {
          const long idx = (long)bz * c_zstride +
                           (long)((rg >> 10) * 8 + (cg >> 9)) * 524288 +
                           (long)(rg & 1023) * 512 + (cg & 511);
          ((u16*)C)[idx] = f2b(val);
        }
      }
    }
  }
}

extern "C" void kernel_launch(void* const* d_in, const int* in_sizes, int n_in,
                              void* d_out, int out_size, void* d_ws, size_t ws_size,
                              hipStream_t stream) {
  const float* x   = (const float*)d_in[0];
  const float* w_k = (const float*)d_in[1];
  const float* w_q = (const float*)d_in[2];
  const float* w_v = (const float*)d_in[3];
  const float* w_u = (const float*)d_in[4];
  const float* b_u = (const float*)d_in[5];
  float* out = (float*)d_out;
  char* ws = (char*)d_ws;

  const long MB = 1048576;
  // ws: xb 0, wqb 4..16 (q,k,v bf16 weights), wub 16, Q 20..52, K 52..84,
  // V 84..116, O 116..148, VT 148..180  (needs ws >= 180MB; satisfied — the
  // previous G=8 layout required the same 180MB and ran)
  u16* xb  = (u16*)(ws);
  u16* wqb = (u16*)(ws + 4 * MB);
  u16* wub = (u16*)(ws + 16 * MB);
  u16* Q   = (u16*)(ws + 20 * MB);
  u16* Kb  = (u16*)(ws + 52 * MB);
  u16* V   = (u16*)(ws + 84 * MB);
  u16* O   = (u16*)(ws + 116 * MB);
  u16* VT  = (u16*)(ws + 148 * MB);

  const dim3 blk(256);

  // fp32 -> bf16 (x, wq, wk, wv, wu)
  cvt_kernel<<<dim3(2048, 5), blk, 0, stream>>>(x, w_q, w_k, w_v, w_u, xb);

  // QKV projections (z-fused): 256 blocks, 512 thr, 128KB LDS
  gemm256_kernel<<<dim3(256), dim3(512), 0, stream>>>(
      xb, 512, wqb, 512, 2097152, Q, 16777216);

  // V -> VT (bh,e,t)
  vt_kernel<<<dim3(16, 8, 32), blk, 0, stream>>>(V, VT);

  // fused flash attention middle: 256 blocks, 512 thr, 152KB LDS
  flash_kernel<<<dim3(256), dim3(512), 0, stream>>>(Q, Kb, VT, O);

  // unify: out = O2d @ w_u^T + b_u (split-K x4, atomics over bias-inited out)
  init_out_kernel<<<2048, blk, 0, stream>>>(out, b_u);
  gemm_kernel<A_HEADBLK, B_PLAIN, C_F32_ATOMIC, false, false, false, true>
      <<<dim3(4, 32, 4), blk, 0, stream>>>(O, 0, 0, wub, 4096, 0, out, 512, 0,
                                           nullptr, 1024, 1.0f);
}